// Round 2
// baseline (427.801 us; speedup 1.0000x reference)
//
#include <hip/hip_runtime.h>

// Problem constants
#define N_NODES 30000
#define NPAD    30080            // 235 * 128
#define N_EDGES 480000
#define N_RELS  8

typedef short bf16x8 __attribute__((ext_vector_type(8)));
typedef float f32x4  __attribute__((ext_vector_type(4)));

__device__ __forceinline__ unsigned short f2bf(float f) {
    unsigned u = __float_as_uint(f);
    u += 0x7fffu + ((u >> 16) & 1u);     // round-to-nearest-even
    return (unsigned short)(u >> 16);
}
__device__ __forceinline__ float bf2f(unsigned short h) {
    return __uint_as_float(((unsigned)h) << 16);
}

__device__ __forceinline__ void load_lds16(const void* g, void* l) {
    __builtin_amdgcn_global_load_lds(
        (const __attribute__((address_space(1))) unsigned int*)g,
        (__attribute__((address_space(3))) unsigned int*)l,
        16, 0, 0);
}

// ---------------------------------------------------------------------------
// K1: cast inputs fp32 -> bf16, pad rows [30000,30080) with zeros
// ---------------------------------------------------------------------------
__global__ void cast_x_kernel(const float* __restrict__ x, unsigned short* __restrict__ xbf) {
    int t = blockIdx.x * 256 + threadIdx.x;          // 962560 threads, 8 elems each
    int base = t * 8;
    int n = base >> 8;
    unsigned short h[8];
    if (n < N_NODES) {
        float4 a = *(const float4*)(x + base);
        float4 b = *(const float4*)(x + base + 4);
        h[0]=f2bf(a.x); h[1]=f2bf(a.y); h[2]=f2bf(a.z); h[3]=f2bf(a.w);
        h[4]=f2bf(b.x); h[5]=f2bf(b.y); h[6]=f2bf(b.z); h[7]=f2bf(b.w);
    } else {
        #pragma unroll
        for (int i = 0; i < 8; ++i) h[i] = 0;
    }
    uint4 o;
    o.x = (unsigned)h[0] | ((unsigned)h[1] << 16);
    o.y = (unsigned)h[2] | ((unsigned)h[3] << 16);
    o.z = (unsigned)h[4] | ((unsigned)h[5] << 16);
    o.w = (unsigned)h[6] | ((unsigned)h[7] << 16);
    *(uint4*)(xbf + base) = o;
}

// ---------------------------------------------------------------------------
// K2: transpose conv_weights [R,H,IN,D] fp32 -> wt[r][c][i] bf16, c = h*64+d
// ---------------------------------------------------------------------------
__global__ void wtrans_kernel(const float* __restrict__ cw, unsigned short* __restrict__ wt) {
    int o = blockIdx.x * 256 + threadIdx.x;          // 524288 threads
    if (o >= N_RELS * 256 * 256) return;
    int i = o & 255;
    int c = (o >> 8) & 255;
    int r = o >> 16;
    float v = cw[(((size_t)r * 4 + (c >> 6)) * 256 + i) * 64 + (c & 63)];
    wt[o] = f2bf(v);
}

// ---------------------------------------------------------------------------
// K3: bf16 MFMA GEMM  feat[r][n][c] = sum_k xbf[n][k] * wt[r][c][k]
//     m97-verbatim structure: 128x128 tile, BK=32, global_load_lds(16B),
//     PLAIN LDS layout (no swizzle), direct scalar bf16 stores (no transpose).
// ---------------------------------------------------------------------------
__global__ __launch_bounds__(256) void gemm_kernel(
    const unsigned short* __restrict__ xbf,   // [NPAD][256]
    const unsigned short* __restrict__ wt,    // [R][256][256]
    unsigned short* __restrict__ feat)        // [R][NPAD][256]
{
    __shared__ __align__(16) unsigned char smem[16384];  // A 8KB | B 8KB

    const int tid  = threadIdx.x;
    const int lane = tid & 63;
    const int w    = tid >> 6;        // wave 0..3
    const int wm   = w >> 1;          // wave row (0/1)
    const int wn   = w & 1;           // wave col (0/1)
    const int quad = lane >> 4;
    const int l15  = lane & 15;

    const int mt = blockIdx.x;                 // 0..234
    const int r  = blockIdx.y >> 1;            // relation
    const int nt = blockIdx.y & 1;             // col tile (0/1)
    const int mbase = mt * 128;
    const int nbase = nt * 128;

    const unsigned short* Asrc = xbf + (size_t)mbase * 256;
    const unsigned short* Bsrc = wt + ((size_t)r * 256 + nbase) * 256;

    f32x4 acc[4][4] = {};

    // staging: lane -> row srow (within 64-row half), chunk c0 (16B of the 64B row)
    const int srow = w * 16 + (lane >> 2);
    const int c0   = lane & 3;

    for (int k0 = 0; k0 < 256; k0 += 32) {
        load_lds16(Asrc + (size_t)srow        * 256 + k0 + c0 * 8, smem + (w * 64) * 16);
        load_lds16(Asrc + (size_t)(64 + srow) * 256 + k0 + c0 * 8, smem + (256 + w * 64) * 16);
        load_lds16(Bsrc + (size_t)srow        * 256 + k0 + c0 * 8, smem + 8192 + (w * 64) * 16);
        load_lds16(Bsrc + (size_t)(64 + srow) * 256 + k0 + c0 * 8, smem + 8192 + (256 + w * 64) * 16);
        __syncthreads();

        bf16x8 af[4], bfr[4];
        #pragma unroll
        for (int i = 0; i < 4; ++i)
            af[i] = *(const bf16x8*)(smem + (wm * 64 + i * 16 + l15) * 64 + quad * 16);
        #pragma unroll
        for (int j = 0; j < 4; ++j)
            bfr[j] = *(const bf16x8*)(smem + 8192 + (wn * 64 + j * 16 + l15) * 64 + quad * 16);

        #pragma unroll
        for (int i = 0; i < 4; ++i)
            #pragma unroll
            for (int j = 0; j < 4; ++j)
                acc[i][j] = __builtin_amdgcn_mfma_f32_16x16x32_bf16(af[i], bfr[j], acc[i][j], 0, 0, 0);
        __syncthreads();
    }

    // epilogue: direct stores in C-layout (row = quad*4+e, col = l15)
    size_t obase = ((size_t)r * NPAD + mbase + wm * 64) * 256 + nbase + wn * 64;
    #pragma unroll
    for (int i = 0; i < 4; ++i)
        #pragma unroll
        for (int j = 0; j < 4; ++j)
            #pragma unroll
            for (int e = 0; e < 4; ++e)
                feat[obase + (size_t)(i * 16 + quad * 4 + e) * 256 + j * 16 + l15] = f2bf(acc[i][j][e]);
}

// ---------------------------------------------------------------------------
// K3b: attention projections from bf16 feat:
//      projl/r[r][n][h] = sum_d feat[r][n][h*64+d] * attn_{l,r}[r][h][d]
// ---------------------------------------------------------------------------
__global__ void proj_kernel(const unsigned short* __restrict__ feat,
                            const float* __restrict__ attn_l, const float* __restrict__ attn_r,
                            float* __restrict__ projl, float* __restrict__ projr)
{
    int t = blockIdx.x * 256 + threadIdx.x;   // [0, NPAD*4)
    int r = blockIdx.y;
    int n = t >> 2, h = t & 3;
    const unsigned short* f = feat + ((size_t)r * NPAD + n) * 256 + h * 64;
    const float* al = attn_l + ((size_t)r * 4 + h) * 64;
    const float* ar = attn_r + ((size_t)r * 4 + h) * 64;
    float sl = 0.f, sr = 0.f;
    #pragma unroll
    for (int c = 0; c < 8; ++c) {
        bf16x8 v8 = *(const bf16x8*)(f + c * 8);
        #pragma unroll
        for (int j = 0; j < 8; ++j) {
            float v = bf2f((unsigned short)v8[j]);
            sl += v * al[c * 8 + j];
            sr += v * ar[c * 8 + j];
        }
    }
    projl[((size_t)r * NPAD + n) * 4 + h] = sl;
    projr[((size_t)r * NPAD + n) * 4 + h] = sr;
}

// ---------------------------------------------------------------------------
// K4: per-edge ex = exp(leaky_relu(el+er)) for 4 heads; histogram by dst
//     (no max-subtraction needed: logits bounded ~±6, exp can't overflow)
// ---------------------------------------------------------------------------
__global__ void edge_logits_kernel(
    const int* __restrict__ esrc, const int* __restrict__ edst, const int* __restrict__ etyp,
    const float* __restrict__ projl, const float* __restrict__ projr,
    float* __restrict__ exbuf, int* __restrict__ counts)
{
    int e = blockIdx.x * 256 + threadIdx.x;
    if (e >= N_EDGES) return;
    int s = esrc[e], d = edst[e], t = etyp[e];
    float4 pl = ((const float4*)projl)[(size_t)t * NPAD + s];
    float4 pr = ((const float4*)projr)[(size_t)t * NPAD + d];
    float4 o;
    float v;
    v = pl.x + pr.x; v = v > 0.f ? v : 0.2f * v; o.x = __expf(v);
    v = pl.y + pr.y; v = v > 0.f ? v : 0.2f * v; o.y = __expf(v);
    v = pl.z + pr.z; v = v > 0.f ? v : 0.2f * v; o.z = __expf(v);
    v = pl.w + pr.w; v = v > 0.f ? v : 0.2f * v; o.w = __expf(v);
    ((float4*)exbuf)[e] = o;
    atomicAdd(&counts[d], 1);
}

// ---------------------------------------------------------------------------
// K5: exclusive scan of counts[30000] -> offsets[30001] and cursor copy
// ---------------------------------------------------------------------------
__global__ void scan_kernel(const int* __restrict__ counts, int* __restrict__ offsets,
                            int* __restrict__ cursor) {
    __shared__ int sm[1024];
    __shared__ int carry_s;
    const int n = N_NODES;
    int tid = threadIdx.x;
    if (tid == 0) carry_s = 0;
    __syncthreads();
    for (int base = 0; base < n; base += 1024) {
        int idx = base + tid;
        int v = (idx < n) ? counts[idx] : 0;
        sm[tid] = v;
        __syncthreads();
        for (int o2 = 1; o2 < 1024; o2 <<= 1) {
            int t2 = (tid >= o2) ? sm[tid - o2] : 0;
            __syncthreads();
            sm[tid] += t2;
            __syncthreads();
        }
        int incl = sm[tid];
        int carry = carry_s;
        if (idx < n) {
            int excl = carry + incl - v;
            offsets[idx] = excl;
            cursor[idx]  = excl;
        }
        __syncthreads();
        if (tid == 1023) carry_s = carry + incl;
        __syncthreads();
    }
    if (tid == 0) offsets[n] = carry_s;
}

// ---------------------------------------------------------------------------
// K6: scatter edge ids into CSR slots
// ---------------------------------------------------------------------------
__global__ void scatter_kernel(const int* __restrict__ edst, int* __restrict__ cursor,
                               int* __restrict__ elist) {
    int e = blockIdx.x * 256 + threadIdx.x;
    if (e >= N_EDGES) return;
    int p = atomicAdd(&cursor[edst[e]], 1);
    elist[p] = e;
}

// ---------------------------------------------------------------------------
// K7: per-node aggregation: one wave per dst node (4 nodes / 256-thr block);
//     single pass computes denominator and ex-weighted sum; out = sum/den + bias
// ---------------------------------------------------------------------------
__global__ __launch_bounds__(256) void aggregate_kernel(
    const int* __restrict__ offsets, const int* __restrict__ elist,
    const int* __restrict__ etyp, const int* __restrict__ esrc,
    const float* __restrict__ exbuf, const unsigned short* __restrict__ feat,
    const float* __restrict__ bias, float* __restrict__ out)
{
    int v = blockIdx.x * 4 + (threadIdx.x >> 6);   // grid 7500 -> v < 30000
    int lane = threadIdx.x & 63;
    int head = lane >> 4;
    int s0 = offsets[v], s1 = offsets[v + 1];
    float a0 = 0.f, a1 = 0.f, a2 = 0.f, a3 = 0.f, den = 0.f;
    for (int i = s0; i < s1; ++i) {
        int e = elist[i];
        int t = etyp[e];
        int s = esrc[e];
        float ex = exbuf[(size_t)e * 4 + head];
        ushort4 f = *(const ushort4*)(feat + ((size_t)t * NPAD + s) * 256 + lane * 4);
        a0 += ex * bf2f(f.x);
        a1 += ex * bf2f(f.y);
        a2 += ex * bf2f(f.z);
        a3 += ex * bf2f(f.w);
        den += ex;
    }
    float inv = den > 0.f ? 1.f / den : 0.f;
    float4 o;
    o.x = a0 * inv + bias[lane * 4 + 0];
    o.y = a1 * inv + bias[lane * 4 + 1];
    o.z = a2 * inv + bias[lane * 4 + 2];
    o.w = a3 * inv + bias[lane * 4 + 3];
    ((float4*)out)[(size_t)v * 64 + lane] = o;
}

// ---------------------------------------------------------------------------
extern "C" void kernel_launch(void* const* d_in, const int* in_sizes, int n_in,
                              void* d_out, int out_size, void* d_ws, size_t ws_size,
                              hipStream_t stream) {
    const float* x    = (const float*)d_in[0];
    const float* cw   = (const float*)d_in[1];
    const float* al   = (const float*)d_in[2];
    const float* ar   = (const float*)d_in[3];
    const float* bias = (const float*)d_in[4];
    const int* esrc   = (const int*)d_in[5];
    const int* edst   = (const int*)d_in[6];
    const int* etyp   = (const int*)d_in[7];
    float* out        = (float*)d_out;

    char* ws = (char*)d_ws;
    size_t off = 0;
    auto alloc = [&](size_t bytes) { size_t o = off; off += (bytes + 255) & ~(size_t)255; return o; };

    unsigned short* xbf  = (unsigned short*)(ws + alloc((size_t)NPAD * 256 * 2));          // 15.4 MB
    unsigned short* wt   = (unsigned short*)(ws + alloc((size_t)N_RELS * 256 * 256 * 2));  // 1 MB
    unsigned short* feat = (unsigned short*)(ws + alloc((size_t)N_RELS * NPAD * 256 * 2)); // 123.2 MB
    float* projl = (float*)(ws + alloc((size_t)N_RELS * NPAD * 4 * 4));                    // 3.85 MB
    float* projr = (float*)(ws + alloc((size_t)N_RELS * NPAD * 4 * 4));                    // 3.85 MB
    float* exbuf = (float*)(ws + alloc((size_t)N_EDGES * 4 * 4));                          // 7.68 MB
    int* counts  = (int*)(ws + alloc((size_t)N_NODES * 4));
    int* offsets = (int*)(ws + alloc((size_t)(N_NODES + 1) * 4));
    int* cursor  = (int*)(ws + alloc((size_t)N_NODES * 4));
    int* elist   = (int*)(ws + alloc((size_t)N_EDGES * 4));
    // total ~157.5 MB

    hipMemsetAsync(counts, 0, (size_t)N_NODES * 4, stream);

    cast_x_kernel<<<3760, 256, 0, stream>>>(x, xbf);
    wtrans_kernel<<<2048, 256, 0, stream>>>(cw, wt);
    gemm_kernel<<<dim3(235, 16), 256, 0, stream>>>(xbf, wt, feat);
    proj_kernel<<<dim3(470, 8), 256, 0, stream>>>(feat, al, ar, projl, projr);
    edge_logits_kernel<<<1875, 256, 0, stream>>>(esrc, edst, etyp, projl, projr, exbuf, counts);
    scan_kernel<<<1, 1024, 0, stream>>>(counts, offsets, cursor);
    scatter_kernel<<<1875, 256, 0, stream>>>(edst, cursor, elist);
    aggregate_kernel<<<7500, 256, 0, stream>>>(offsets, elist, etyp, esrc, exbuf, feat, bias, out);
}

// Round 3
// 333.338 us; speedup vs baseline: 1.2834x; 1.2834x over previous
//
#include <hip/hip_runtime.h>

// Problem constants
#define N_NODES 30000
#define NPAD    30080            // 235 * 128
#define N_EDGES 480000
#define N_RELS  8
#define NB_SCAN 118              // ceil(30000/256)

typedef short bf16x8 __attribute__((ext_vector_type(8)));
typedef float f32x4  __attribute__((ext_vector_type(4)));

__device__ __forceinline__ unsigned short f2bf(float f) {
    unsigned u = __float_as_uint(f);
    u += 0x7fffu + ((u >> 16) & 1u);     // round-to-nearest-even
    return (unsigned short)(u >> 16);
}
__device__ __forceinline__ float bf2f(unsigned short h) {
    return __uint_as_float(((unsigned)h) << 16);
}

__device__ __forceinline__ void load_lds16(const void* g, void* l) {
    __builtin_amdgcn_global_load_lds(
        (const __attribute__((address_space(1))) unsigned int*)g,
        (__attribute__((address_space(3))) unsigned int*)l,
        16, 0, 0);
}

// ---------------------------------------------------------------------------
// K1: cast inputs fp32 -> bf16, pad rows [30000,30080) with zeros
// ---------------------------------------------------------------------------
__global__ void cast_x_kernel(const float* __restrict__ x, unsigned short* __restrict__ xbf) {
    int t = blockIdx.x * 256 + threadIdx.x;          // 962560 threads, 8 elems each
    int base = t * 8;
    int n = base >> 8;
    unsigned short h[8];
    if (n < N_NODES) {
        float4 a = *(const float4*)(x + base);
        float4 b = *(const float4*)(x + base + 4);
        h[0]=f2bf(a.x); h[1]=f2bf(a.y); h[2]=f2bf(a.z); h[3]=f2bf(a.w);
        h[4]=f2bf(b.x); h[5]=f2bf(b.y); h[6]=f2bf(b.z); h[7]=f2bf(b.w);
    } else {
        #pragma unroll
        for (int i = 0; i < 8; ++i) h[i] = 0;
    }
    uint4 o;
    o.x = (unsigned)h[0] | ((unsigned)h[1] << 16);
    o.y = (unsigned)h[2] | ((unsigned)h[3] << 16);
    o.z = (unsigned)h[4] | ((unsigned)h[5] << 16);
    o.w = (unsigned)h[6] | ((unsigned)h[7] << 16);
    *(uint4*)(xbf + base) = o;
}

// ---------------------------------------------------------------------------
// K2: transpose conv_weights [R,H,IN,D] fp32 -> wt[r][c][i] bf16, c = h*64+d
// ---------------------------------------------------------------------------
__global__ void wtrans_kernel(const float* __restrict__ cw, unsigned short* __restrict__ wt) {
    int o = blockIdx.x * 256 + threadIdx.x;          // 524288 threads
    if (o >= N_RELS * 256 * 256) return;
    int i = o & 255;
    int c = (o >> 8) & 255;
    int r = o >> 16;
    float v = cw[(((size_t)r * 4 + (c >> 6)) * 256 + i) * 64 + (c & 63)];
    wt[o] = f2bf(v);
}

// ---------------------------------------------------------------------------
// K2b: histogram of destination nodes
// ---------------------------------------------------------------------------
__global__ void hist_kernel(const int* __restrict__ edst, int* __restrict__ counts) {
    int e = blockIdx.x * 256 + threadIdx.x;
    if (e < N_EDGES) atomicAdd(&counts[edst[e]], 1);
}

// ---------------------------------------------------------------------------
// K2c/d/e: three-phase exclusive scan of counts -> offsets (+cursor copy)
// ---------------------------------------------------------------------------
__global__ void scan1_kernel(const int* __restrict__ counts, int* __restrict__ locexcl,
                             int* __restrict__ bsum) {
    __shared__ int sm[256];
    int tid = threadIdx.x;
    int idx = blockIdx.x * 256 + tid;
    int v = (idx < N_NODES) ? counts[idx] : 0;
    sm[tid] = v;
    __syncthreads();
    for (int o = 1; o < 256; o <<= 1) {
        int t = (tid >= o) ? sm[tid - o] : 0;
        __syncthreads();
        sm[tid] += t;
        __syncthreads();
    }
    int incl = sm[tid];
    if (idx < N_NODES) locexcl[idx] = incl - v;
    if (tid == 255) bsum[blockIdx.x] = incl;
}

__global__ void scan2_kernel(const int* __restrict__ bsum, int* __restrict__ bpre) {
    __shared__ int sm[128];
    int tid = threadIdx.x;
    int v = (tid < NB_SCAN) ? bsum[tid] : 0;
    sm[tid] = v;
    __syncthreads();
    for (int o = 1; o < 128; o <<= 1) {
        int t = (tid >= o) ? sm[tid - o] : 0;
        __syncthreads();
        sm[tid] += t;
        __syncthreads();
    }
    if (tid < NB_SCAN) bpre[tid] = sm[tid] - v;
}

__global__ void scan3_kernel(const int* __restrict__ locexcl, const int* __restrict__ bpre,
                             int* __restrict__ offsets, int* __restrict__ cursor) {
    int idx = blockIdx.x * 256 + threadIdx.x;
    if (idx < N_NODES) {
        int o = bpre[blockIdx.x] + locexcl[idx];
        offsets[idx] = o;
        cursor[idx]  = o;
    }
    if (idx == 0) offsets[N_NODES] = N_EDGES;
}

// ---------------------------------------------------------------------------
// K3: bf16 MFMA GEMM  feat[r][n][c] = sum_k xbf[n][k] * wt[r][c][k]
//     m97 structure: 128x128 tile, BK=32, global_load_lds(16B),
//     plain LDS layout, direct scalar bf16 stores.
// ---------------------------------------------------------------------------
__global__ __launch_bounds__(256) void gemm_kernel(
    const unsigned short* __restrict__ xbf,   // [NPAD][256]
    const unsigned short* __restrict__ wt,    // [R][256][256]
    unsigned short* __restrict__ feat)        // [R][NPAD][256]
{
    __shared__ __align__(16) unsigned char smem[16384];  // A 8KB | B 8KB

    const int tid  = threadIdx.x;
    const int lane = tid & 63;
    const int w    = tid >> 6;        // wave 0..3
    const int wm   = w >> 1;          // wave row (0/1)
    const int wn   = w & 1;           // wave col (0/1)
    const int quad = lane >> 4;
    const int l15  = lane & 15;

    const int mt = blockIdx.x;                 // 0..234
    const int r  = blockIdx.y >> 1;            // relation
    const int nt = blockIdx.y & 1;             // col tile (0/1)
    const int mbase = mt * 128;
    const int nbase = nt * 128;

    const unsigned short* Asrc = xbf + (size_t)mbase * 256;
    const unsigned short* Bsrc = wt + ((size_t)r * 256 + nbase) * 256;

    f32x4 acc[4][4] = {};

    const int srow = w * 16 + (lane >> 2);
    const int c0   = lane & 3;

    for (int k0 = 0; k0 < 256; k0 += 32) {
        load_lds16(Asrc + (size_t)srow        * 256 + k0 + c0 * 8, smem + (w * 64) * 16);
        load_lds16(Asrc + (size_t)(64 + srow) * 256 + k0 + c0 * 8, smem + (256 + w * 64) * 16);
        load_lds16(Bsrc + (size_t)srow        * 256 + k0 + c0 * 8, smem + 8192 + (w * 64) * 16);
        load_lds16(Bsrc + (size_t)(64 + srow) * 256 + k0 + c0 * 8, smem + 8192 + (256 + w * 64) * 16);
        __syncthreads();

        bf16x8 af[4], bfr[4];
        #pragma unroll
        for (int i = 0; i < 4; ++i)
            af[i] = *(const bf16x8*)(smem + (wm * 64 + i * 16 + l15) * 64 + quad * 16);
        #pragma unroll
        for (int j = 0; j < 4; ++j)
            bfr[j] = *(const bf16x8*)(smem + 8192 + (wn * 64 + j * 16 + l15) * 64 + quad * 16);

        #pragma unroll
        for (int i = 0; i < 4; ++i)
            #pragma unroll
            for (int j = 0; j < 4; ++j)
                acc[i][j] = __builtin_amdgcn_mfma_f32_16x16x32_bf16(af[i], bfr[j], acc[i][j], 0, 0, 0);
        __syncthreads();
    }

    size_t obase = ((size_t)r * NPAD + mbase + wm * 64) * 256 + nbase + wn * 64;
    #pragma unroll
    for (int i = 0; i < 4; ++i)
        #pragma unroll
        for (int j = 0; j < 4; ++j)
            #pragma unroll
            for (int e = 0; e < 4; ++e)
                feat[obase + (size_t)(i * 16 + quad * 4 + e) * 256 + j * 16 + l15] = f2bf(acc[i][j][e]);
}

// ---------------------------------------------------------------------------
// K3b: attention projections from bf16 feat
// ---------------------------------------------------------------------------
__global__ void proj_kernel(const unsigned short* __restrict__ feat,
                            const float* __restrict__ attn_l, const float* __restrict__ attn_r,
                            float* __restrict__ projl, float* __restrict__ projr)
{
    int t = blockIdx.x * 256 + threadIdx.x;   // [0, NPAD*4)
    int r = blockIdx.y;
    int n = t >> 2, h = t & 3;
    const unsigned short* f = feat + ((size_t)r * NPAD + n) * 256 + h * 64;
    const float* al = attn_l + ((size_t)r * 4 + h) * 64;
    const float* ar = attn_r + ((size_t)r * 4 + h) * 64;
    float sl = 0.f, sr = 0.f;
    #pragma unroll
    for (int c = 0; c < 8; ++c) {
        bf16x8 v8 = *(const bf16x8*)(f + c * 8);
        #pragma unroll
        for (int j = 0; j < 8; ++j) {
            float v = bf2f((unsigned short)v8[j]);
            sl += v * al[c * 8 + j];
            sr += v * ar[c * 8 + j];
        }
    }
    projl[((size_t)r * NPAD + n) * 4 + h] = sl;
    projr[((size_t)r * NPAD + n) * 4 + h] = sr;
}

// ---------------------------------------------------------------------------
// K4: fused per-edge logits + CSR scatter with payload:
//     srcoff[p] = t*NPAD+s  and  exw[p] = float4 of exp(leaky_relu(el+er))
// ---------------------------------------------------------------------------
__global__ void logits_scatter_kernel(
    const int* __restrict__ esrc, const int* __restrict__ edst, const int* __restrict__ etyp,
    const float* __restrict__ projl, const float* __restrict__ projr,
    int* __restrict__ cursor, int* __restrict__ srcoff, float* __restrict__ exw)
{
    int e = blockIdx.x * 256 + threadIdx.x;
    if (e >= N_EDGES) return;
    int s = esrc[e], d = edst[e], t = etyp[e];
    float4 pl = ((const float4*)projl)[(size_t)t * NPAD + s];
    float4 pr = ((const float4*)projr)[(size_t)t * NPAD + d];
    float4 o;
    float v;
    v = pl.x + pr.x; v = v > 0.f ? v : 0.2f * v; o.x = __expf(v);
    v = pl.y + pr.y; v = v > 0.f ? v : 0.2f * v; o.y = __expf(v);
    v = pl.z + pr.z; v = v > 0.f ? v : 0.2f * v; o.z = __expf(v);
    v = pl.w + pr.w; v = v > 0.f ? v : 0.2f * v; o.w = __expf(v);
    int p = atomicAdd(&cursor[d], 1);
    srcoff[p] = t * NPAD + s;
    ((float4*)exw)[p] = o;
}

// ---------------------------------------------------------------------------
// K7: per-node aggregation: one wave per dst node (4 nodes / block).
//     Streams srcoff/exw sequentially; 4 independent feat gathers in flight.
// ---------------------------------------------------------------------------
__global__ __launch_bounds__(256) void aggregate_kernel(
    const int* __restrict__ offsets, const int* __restrict__ srcoff,
    const float* __restrict__ exw, const unsigned short* __restrict__ feat,
    const float* __restrict__ bias, float* __restrict__ out)
{
    int v = blockIdx.x * 4 + (threadIdx.x >> 6);   // grid 7500 -> v < 30000
    int lane = threadIdx.x & 63;
    int head = lane >> 4;
    int s0 = offsets[v], s1 = offsets[v + 1];
    float a0 = 0.f, a1 = 0.f, a2 = 0.f, a3 = 0.f, den = 0.f;
    int i = s0;
    for (; i + 4 <= s1; i += 4) {
        int o0 = srcoff[i], o1 = srcoff[i + 1], o2 = srcoff[i + 2], o3 = srcoff[i + 3];
        float e0 = exw[(size_t)i * 4 + head];
        float e1 = exw[(size_t)(i + 1) * 4 + head];
        float e2 = exw[(size_t)(i + 2) * 4 + head];
        float e3 = exw[(size_t)(i + 3) * 4 + head];
        ushort4 f0 = *(const ushort4*)(feat + (size_t)o0 * 256 + lane * 4);
        ushort4 f1 = *(const ushort4*)(feat + (size_t)o1 * 256 + lane * 4);
        ushort4 f2 = *(const ushort4*)(feat + (size_t)o2 * 256 + lane * 4);
        ushort4 f3 = *(const ushort4*)(feat + (size_t)o3 * 256 + lane * 4);
        den += (e0 + e1) + (e2 + e3);
        a0 += e0 * bf2f(f0.x) + e1 * bf2f(f1.x) + e2 * bf2f(f2.x) + e3 * bf2f(f3.x);
        a1 += e0 * bf2f(f0.y) + e1 * bf2f(f1.y) + e2 * bf2f(f2.y) + e3 * bf2f(f3.y);
        a2 += e0 * bf2f(f0.z) + e1 * bf2f(f1.z) + e2 * bf2f(f2.z) + e3 * bf2f(f3.z);
        a3 += e0 * bf2f(f0.w) + e1 * bf2f(f1.w) + e2 * bf2f(f2.w) + e3 * bf2f(f3.w);
    }
    for (; i < s1; ++i) {
        int o0 = srcoff[i];
        float e0 = exw[(size_t)i * 4 + head];
        ushort4 f0 = *(const ushort4*)(feat + (size_t)o0 * 256 + lane * 4);
        den += e0;
        a0 += e0 * bf2f(f0.x);
        a1 += e0 * bf2f(f0.y);
        a2 += e0 * bf2f(f0.z);
        a3 += e0 * bf2f(f0.w);
    }
    float inv = den > 0.f ? 1.f / den : 0.f;
    float4 o;
    o.x = a0 * inv + bias[lane * 4 + 0];
    o.y = a1 * inv + bias[lane * 4 + 1];
    o.z = a2 * inv + bias[lane * 4 + 2];
    o.w = a3 * inv + bias[lane * 4 + 3];
    ((float4*)out)[(size_t)v * 64 + lane] = o;
}

// ---------------------------------------------------------------------------
extern "C" void kernel_launch(void* const* d_in, const int* in_sizes, int n_in,
                              void* d_out, int out_size, void* d_ws, size_t ws_size,
                              hipStream_t stream) {
    const float* x    = (const float*)d_in[0];
    const float* cw   = (const float*)d_in[1];
    const float* al   = (const float*)d_in[2];
    const float* ar   = (const float*)d_in[3];
    const float* bias = (const float*)d_in[4];
    const int* esrc   = (const int*)d_in[5];
    const int* edst   = (const int*)d_in[6];
    const int* etyp   = (const int*)d_in[7];
    float* out        = (float*)d_out;

    char* ws = (char*)d_ws;
    size_t off = 0;
    auto alloc = [&](size_t bytes) { size_t o = off; off += (bytes + 255) & ~(size_t)255; return o; };

    unsigned short* xbf  = (unsigned short*)(ws + alloc((size_t)NPAD * 256 * 2));          // 15.4 MB
    unsigned short* wt   = (unsigned short*)(ws + alloc((size_t)N_RELS * 256 * 256 * 2));  // 1 MB
    unsigned short* feat = (unsigned short*)(ws + alloc((size_t)N_RELS * NPAD * 256 * 2)); // 123.2 MB
    float* projl = (float*)(ws + alloc((size_t)N_RELS * NPAD * 4 * 4));                    // 3.85 MB
    float* projr = (float*)(ws + alloc((size_t)N_RELS * NPAD * 4 * 4));                    // 3.85 MB
    float* exw   = (float*)(ws + alloc((size_t)N_EDGES * 4 * 4));                          // 7.68 MB
    int* srcoff  = (int*)(ws + alloc((size_t)N_EDGES * 4));                                // 1.92 MB
    int* counts  = (int*)(ws + alloc((size_t)N_NODES * 4));
    int* offsets = (int*)(ws + alloc((size_t)(N_NODES + 1) * 4));
    int* cursor  = (int*)(ws + alloc((size_t)N_NODES * 4));
    int* locexcl = (int*)(ws + alloc((size_t)N_NODES * 4));
    int* bsum    = (int*)(ws + alloc((size_t)NB_SCAN * 4));
    int* bpre    = (int*)(ws + alloc((size_t)NB_SCAN * 4));

    hipMemsetAsync(counts, 0, (size_t)N_NODES * 4, stream);

    cast_x_kernel<<<3760, 256, 0, stream>>>(x, xbf);
    wtrans_kernel<<<2048, 256, 0, stream>>>(cw, wt);
    hist_kernel<<<1875, 256, 0, stream>>>(edst, counts);
    scan1_kernel<<<NB_SCAN, 256, 0, stream>>>(counts, locexcl, bsum);
    scan2_kernel<<<1, 128, 0, stream>>>(bsum, bpre);
    scan3_kernel<<<NB_SCAN, 256, 0, stream>>>(locexcl, bpre, offsets, cursor);
    gemm_kernel<<<dim3(235, 16), 256, 0, stream>>>(xbf, wt, feat);
    proj_kernel<<<dim3(470, 8), 256, 0, stream>>>(feat, al, ar, projl, projr);
    logits_scatter_kernel<<<1875, 256, 0, stream>>>(esrc, edst, etyp, projl, projr,
                                                    cursor, srcoff, exw);
    aggregate_kernel<<<7500, 256, 0, stream>>>(offsets, srcoff, exw, feat, bias, out);
}

// Round 5
// 270.778 us; speedup vs baseline: 1.5799x; 1.2310x over previous
//
#include <hip/hip_runtime.h>

// Problem constants
#define N_NODES 30000
#define NPAD    30080            // 235 * 128
#define N_EDGES 480000
#define N_RELS  8
#define NB_SCAN 118              // ceil(30000/256)

typedef short bf16x8 __attribute__((ext_vector_type(8)));
typedef float f32x4  __attribute__((ext_vector_type(4)));

__device__ __forceinline__ unsigned short f2bf(float f) {
    unsigned u = __float_as_uint(f);
    u += 0x7fffu + ((u >> 16) & 1u);     // round-to-nearest-even
    return (unsigned short)(u >> 16);
}
__device__ __forceinline__ float bf2f(unsigned short h) {
    return __uint_as_float(((unsigned)h) << 16);
}

__device__ __forceinline__ void load_lds16(const void* g, void* l) {
    __builtin_amdgcn_global_load_lds(
        (const __attribute__((address_space(1))) unsigned int*)g,
        (__attribute__((address_space(3))) unsigned int*)l,
        16, 0, 0);
}

// ---------------------------------------------------------------------------
// K1: cast inputs fp32 -> bf16, pad rows [30000,30080) with zeros
// ---------------------------------------------------------------------------
__global__ void cast_x_kernel(const float* __restrict__ x, unsigned short* __restrict__ xbf) {
    int t = blockIdx.x * 256 + threadIdx.x;          // 962560 threads, 8 elems each
    int base = t * 8;
    int n = base >> 8;
    unsigned short h[8];
    if (n < N_NODES) {
        float4 a = *(const float4*)(x + base);
        float4 b = *(const float4*)(x + base + 4);
        h[0]=f2bf(a.x); h[1]=f2bf(a.y); h[2]=f2bf(a.z); h[3]=f2bf(a.w);
        h[4]=f2bf(b.x); h[5]=f2bf(b.y); h[6]=f2bf(b.z); h[7]=f2bf(b.w);
    } else {
        #pragma unroll
        for (int i = 0; i < 8; ++i) h[i] = 0;
    }
    uint4 o;
    o.x = (unsigned)h[0] | ((unsigned)h[1] << 16);
    o.y = (unsigned)h[2] | ((unsigned)h[3] << 16);
    o.z = (unsigned)h[4] | ((unsigned)h[5] << 16);
    o.w = (unsigned)h[6] | ((unsigned)h[7] << 16);
    *(uint4*)(xbf + base) = o;
}

// ---------------------------------------------------------------------------
// K2: transpose conv_weights [R,H,IN,D] fp32 -> wt[r][c][i] bf16, c = h*64+d
// ---------------------------------------------------------------------------
__global__ void wtrans_kernel(const float* __restrict__ cw, unsigned short* __restrict__ wt) {
    int o = blockIdx.x * 256 + threadIdx.x;          // 524288 threads
    if (o >= N_RELS * 256 * 256) return;
    int i = o & 255;
    int c = (o >> 8) & 255;
    int r = o >> 16;
    float v = cw[(((size_t)r * 4 + (c >> 6)) * 256 + i) * 64 + (c & 63)];
    wt[o] = f2bf(v);
}

// ---------------------------------------------------------------------------
// K2b: histogram of destination nodes
// ---------------------------------------------------------------------------
__global__ void hist_kernel(const int* __restrict__ edst, int* __restrict__ counts) {
    int e = blockIdx.x * 256 + threadIdx.x;
    if (e < N_EDGES) atomicAdd(&counts[edst[e]], 1);
}

// ---------------------------------------------------------------------------
// K2c/d/e: three-phase exclusive scan of counts -> offsets (+cursor copy)
// ---------------------------------------------------------------------------
__global__ void scan1_kernel(const int* __restrict__ counts, int* __restrict__ locexcl,
                             int* __restrict__ bsum) {
    __shared__ int sm[256];
    int tid = threadIdx.x;
    int idx = blockIdx.x * 256 + tid;
    int v = (idx < N_NODES) ? counts[idx] : 0;
    sm[tid] = v;
    __syncthreads();
    for (int o = 1; o < 256; o <<= 1) {
        int t = (tid >= o) ? sm[tid - o] : 0;
        __syncthreads();
        sm[tid] += t;
        __syncthreads();
    }
    int incl = sm[tid];
    if (idx < N_NODES) locexcl[idx] = incl - v;
    if (tid == 255) bsum[blockIdx.x] = incl;
}

__global__ void scan2_kernel(const int* __restrict__ bsum, int* __restrict__ bpre) {
    __shared__ int sm[128];
    int tid = threadIdx.x;
    int v = (tid < NB_SCAN) ? bsum[tid] : 0;
    sm[tid] = v;
    __syncthreads();
    for (int o = 1; o < 128; o <<= 1) {
        int t = (tid >= o) ? sm[tid - o] : 0;
        __syncthreads();
        sm[tid] += t;
        __syncthreads();
    }
    if (tid < NB_SCAN) bpre[tid] = sm[tid] - v;
}

__global__ void scan3_kernel(const int* __restrict__ locexcl, const int* __restrict__ bpre,
                             int* __restrict__ offsets, int* __restrict__ cursor) {
    int idx = blockIdx.x * 256 + threadIdx.x;
    if (idx < N_NODES) {
        int o = bpre[blockIdx.x] + locexcl[idx];
        offsets[idx] = o;
        cursor[idx]  = o;
    }
    if (idx == 0) offsets[N_NODES] = N_EDGES;
}

// ---------------------------------------------------------------------------
// K3: bf16 MFMA GEMM  feat[r][n][c] = sum_k xbf[n][k] * wt[r][c][k]
//     m97 structure: 128x128 tile, BK=32, global_load_lds(16B), plain LDS
//     layout, direct scalar bf16 stores.
//     Fused epilogue 2: proj_l/r via per-wave LDS reduction (NOT shuffles —
//     the shuffle-butterfly variant failed on HW twice, rounds 1 & 4).
// ---------------------------------------------------------------------------
__global__ __launch_bounds__(256) void gemm_kernel(
    const unsigned short* __restrict__ xbf,   // [NPAD][256]
    const unsigned short* __restrict__ wt,    // [R][256][256]
    const float* __restrict__ attn_l,         // [R][4][64]
    const float* __restrict__ attn_r,
    unsigned short* __restrict__ feat,        // [R][NPAD][256]
    float* __restrict__ projl,                // [R][NPAD][4]
    float* __restrict__ projr)
{
    // first 16 KB: A|B staging during K-loop, then proj-L reduction buffer;
    // upper 16 KB: proj-R reduction buffer.
    __shared__ __align__(16) unsigned char smem[32768];

    const int tid  = threadIdx.x;
    const int lane = tid & 63;
    const int w    = tid >> 6;        // wave 0..3
    const int wm   = w >> 1;          // wave row (0/1)
    const int wn   = w & 1;           // wave col (0/1)
    const int quad = lane >> 4;
    const int l15  = lane & 15;

    const int mt = blockIdx.x;                 // 0..234
    const int r  = blockIdx.y >> 1;            // relation
    const int nt = blockIdx.y & 1;             // col tile (0/1)
    const int mbase = mt * 128;
    const int nbase = nt * 128;

    const unsigned short* Asrc = xbf + (size_t)mbase * 256;
    const unsigned short* Bsrc = wt + ((size_t)r * 256 + nbase) * 256;

    f32x4 acc[4][4] = {};

    const int srow = w * 16 + (lane >> 2);
    const int c0   = lane & 3;

    for (int k0 = 0; k0 < 256; k0 += 32) {
        load_lds16(Asrc + (size_t)srow        * 256 + k0 + c0 * 8, smem + (w * 64) * 16);
        load_lds16(Asrc + (size_t)(64 + srow) * 256 + k0 + c0 * 8, smem + (256 + w * 64) * 16);
        load_lds16(Bsrc + (size_t)srow        * 256 + k0 + c0 * 8, smem + 8192 + (w * 64) * 16);
        load_lds16(Bsrc + (size_t)(64 + srow) * 256 + k0 + c0 * 8, smem + 8192 + (256 + w * 64) * 16);
        __syncthreads();

        bf16x8 af[4], bfr[4];
        #pragma unroll
        for (int i = 0; i < 4; ++i)
            af[i] = *(const bf16x8*)(smem + (wm * 64 + i * 16 + l15) * 64 + quad * 16);
        #pragma unroll
        for (int j = 0; j < 4; ++j)
            bfr[j] = *(const bf16x8*)(smem + 8192 + (wn * 64 + j * 16 + l15) * 64 + quad * 16);

        #pragma unroll
        for (int i = 0; i < 4; ++i)
            #pragma unroll
            for (int j = 0; j < 4; ++j)
                acc[i][j] = __builtin_amdgcn_mfma_f32_16x16x32_bf16(af[i], bfr[j], acc[i][j], 0, 0, 0);
        __syncthreads();
    }

    // ---- epilogue 1: feat bf16, direct stores in C-layout (row=quad*4+e, col=l15)
    size_t obase = ((size_t)r * NPAD + mbase + wm * 64) * 256 + nbase + wn * 64;
    #pragma unroll
    for (int i = 0; i < 4; ++i)
        #pragma unroll
        for (int j = 0; j < 4; ++j)
            #pragma unroll
            for (int e = 0; e < 4; ++e)
                feat[obase + (size_t)(i * 16 + quad * 4 + e) * 256 + j * 16 + l15] = f2bf(acc[i][j][e]);

    // ---- epilogue 2: fused attention projections via per-wave LDS reduction.
    // Per-lane partial over this lane's 4 col-groups, then LDS row gather.
    // Each wave touches only its own disjoint 4KB region -> no __syncthreads.
    const int head = nt * 2 + wn;
    float al[4], ar[4];
    #pragma unroll
    for (int j = 0; j < 4; ++j) {
        al[j] = attn_l[((size_t)r * 4 + head) * 64 + j * 16 + l15];
        ar[j] = attn_r[((size_t)r * 4 + head) * 64 + j * 16 + l15];
    }
    float* bufL = (float*)smem + w * 1024;            // 64 rows x 16 partials
    float* bufR = (float*)(smem + 16384) + w * 1024;
    #pragma unroll
    for (int i = 0; i < 4; ++i)
        #pragma unroll
        for (int e = 0; e < 4; ++e) {
            float s1 = 0.f, s2 = 0.f;
            #pragma unroll
            for (int j = 0; j < 4; ++j) {
                s1 += acc[i][j][e] * al[j];
                s2 += acc[i][j][e] * ar[j];
            }
            int row = i * 16 + quad * 4 + e;          // local row, 0..63
            bufL[row * 16 + l15] = s1;
            bufR[row * 16 + l15] = s2;
        }
    // each lane reduces one full row (its own wave's region; in-wave DS order
    // guarantees the writes above are visible)
    float sL = 0.f, sR = 0.f;
    #pragma unroll
    for (int c = 0; c < 4; ++c) {
        float4 vl = *(const float4*)(bufL + lane * 16 + c * 4);
        float4 vr = *(const float4*)(bufR + lane * 16 + c * 4);
        sL += (vl.x + vl.y) + (vl.z + vl.w);
        sR += (vr.x + vr.y) + (vr.z + vr.w);
    }
    int g = mbase + wm * 64 + lane;
    projl[((size_t)r * NPAD + g) * 4 + head] = sL;
    projr[((size_t)r * NPAD + g) * 4 + head] = sR;
}

// ---------------------------------------------------------------------------
// K4: fused per-edge logits + CSR scatter with payload:
//     srcoff[p] = t*NPAD+s  and  exw[p] = float4 of exp(leaky_relu(el+er))
// ---------------------------------------------------------------------------
__global__ void logits_scatter_kernel(
    const int* __restrict__ esrc, const int* __restrict__ edst, const int* __restrict__ etyp,
    const float* __restrict__ projl, const float* __restrict__ projr,
    int* __restrict__ cursor, int* __restrict__ srcoff, float* __restrict__ exw)
{
    int e = blockIdx.x * 256 + threadIdx.x;
    if (e >= N_EDGES) return;
    int s = esrc[e], d = edst[e], t = etyp[e];
    float4 pl = ((const float4*)projl)[(size_t)t * NPAD + s];
    float4 pr = ((const float4*)projr)[(size_t)t * NPAD + d];
    float4 o;
    float v;
    v = pl.x + pr.x; v = v > 0.f ? v : 0.2f * v; o.x = __expf(v);
    v = pl.y + pr.y; v = v > 0.f ? v : 0.2f * v; o.y = __expf(v);
    v = pl.z + pr.z; v = v > 0.f ? v : 0.2f * v; o.z = __expf(v);
    v = pl.w + pr.w; v = v > 0.f ? v : 0.2f * v; o.w = __expf(v);
    int p = atomicAdd(&cursor[d], 1);
    srcoff[p] = t * NPAD + s;
    ((float4*)exw)[p] = o;
}

// ---------------------------------------------------------------------------
// K7: per-node aggregation: one wave per dst node (4 nodes / block).
//     Streams srcoff/exw sequentially; 4 independent feat gathers in flight.
// ---------------------------------------------------------------------------
__global__ __launch_bounds__(256) void aggregate_kernel(
    const int* __restrict__ offsets, const int* __restrict__ srcoff,
    const float* __restrict__ exw, const unsigned short* __restrict__ feat,
    const float* __restrict__ bias, float* __restrict__ out)
{
    int v = blockIdx.x * 4 + (threadIdx.x >> 6);   // grid 7500 -> v < 30000
    int lane = threadIdx.x & 63;
    int head = lane >> 4;
    int s0 = offsets[v], s1 = offsets[v + 1];
    float a0 = 0.f, a1 = 0.f, a2 = 0.f, a3 = 0.f, den = 0.f;
    int i = s0;
    for (; i + 4 <= s1; i += 4) {
        int o0 = srcoff[i], o1 = srcoff[i + 1], o2 = srcoff[i + 2], o3 = srcoff[i + 3];
        float e0 = exw[(size_t)i * 4 + head];
        float e1 = exw[(size_t)(i + 1) * 4 + head];
        float e2 = exw[(size_t)(i + 2) * 4 + head];
        float e3 = exw[(size_t)(i + 3) * 4 + head];
        ushort4 f0 = *(const ushort4*)(feat + (size_t)o0 * 256 + lane * 4);
        ushort4 f1 = *(const ushort4*)(feat + (size_t)o1 * 256 + lane * 4);
        ushort4 f2 = *(const ushort4*)(feat + (size_t)o2 * 256 + lane * 4);
        ushort4 f3 = *(const ushort4*)(feat + (size_t)o3 * 256 + lane * 4);
        den += (e0 + e1) + (e2 + e3);
        a0 += e0 * bf2f(f0.x) + e1 * bf2f(f1.x) + e2 * bf2f(f2.x) + e3 * bf2f(f3.x);
        a1 += e0 * bf2f(f0.y) + e1 * bf2f(f1.y) + e2 * bf2f(f2.y) + e3 * bf2f(f3.y);
        a2 += e0 * bf2f(f0.z) + e1 * bf2f(f1.z) + e2 * bf2f(f2.z) + e3 * bf2f(f3.z);
        a3 += e0 * bf2f(f0.w) + e1 * bf2f(f1.w) + e2 * bf2f(f2.w) + e3 * bf2f(f3.w);
    }
    for (; i < s1; ++i) {
        int o0 = srcoff[i];
        float e0 = exw[(size_t)i * 4 + head];
        ushort4 f0 = *(const ushort4*)(feat + (size_t)o0 * 256 + lane * 4);
        den += e0;
        a0 += e0 * bf2f(f0.x);
        a1 += e0 * bf2f(f0.y);
        a2 += e0 * bf2f(f0.z);
        a3 += e0 * bf2f(f0.w);
    }
    float inv = den > 0.f ? 1.f / den : 0.f;
    float4 o;
    o.x = a0 * inv + bias[lane * 4 + 0];
    o.y = a1 * inv + bias[lane * 4 + 1];
    o.z = a2 * inv + bias[lane * 4 + 2];
    o.w = a3 * inv + bias[lane * 4 + 3];
    ((float4*)out)[(size_t)v * 64 + lane] = o;
}

// ---------------------------------------------------------------------------
extern "C" void kernel_launch(void* const* d_in, const int* in_sizes, int n_in,
                              void* d_out, int out_size, void* d_ws, size_t ws_size,
                              hipStream_t stream) {
    const float* x    = (const float*)d_in[0];
    const float* cw   = (const float*)d_in[1];
    const float* al   = (const float*)d_in[2];
    const float* ar   = (const float*)d_in[3];
    const float* bias = (const float*)d_in[4];
    const int* esrc   = (const int*)d_in[5];
    const int* edst   = (const int*)d_in[6];
    const int* etyp   = (const int*)d_in[7];
    float* out        = (float*)d_out;

    char* ws = (char*)d_ws;
    size_t off = 0;
    auto alloc = [&](size_t bytes) { size_t o = off; off += (bytes + 255) & ~(size_t)255; return o; };

    unsigned short* xbf  = (unsigned short*)(ws + alloc((size_t)NPAD * 256 * 2));          // 15.4 MB
    unsigned short* wt   = (unsigned short*)(ws + alloc((size_t)N_RELS * 256 * 256 * 2));  // 1 MB
    unsigned short* feat = (unsigned short*)(ws + alloc((size_t)N_RELS * NPAD * 256 * 2)); // 123.2 MB
    float* projl = (float*)(ws + alloc((size_t)N_RELS * NPAD * 4 * 4));                    // 3.85 MB
    float* projr = (float*)(ws + alloc((size_t)N_RELS * NPAD * 4 * 4));                    // 3.85 MB
    float* exw   = (float*)(ws + alloc((size_t)N_EDGES * 4 * 4));                          // 7.68 MB
    int* srcoff  = (int*)(ws + alloc((size_t)N_EDGES * 4));                                // 1.92 MB
    int* counts  = (int*)(ws + alloc((size_t)N_NODES * 4));
    int* offsets = (int*)(ws + alloc((size_t)(N_NODES + 1) * 4));
    int* cursor  = (int*)(ws + alloc((size_t)N_NODES * 4));
    int* locexcl = (int*)(ws + alloc((size_t)N_NODES * 4));
    int* bsum    = (int*)(ws + alloc((size_t)NB_SCAN * 4));
    int* bpre    = (int*)(ws + alloc((size_t)NB_SCAN * 4));

    hipMemsetAsync(counts, 0, (size_t)N_NODES * 4, stream);

    cast_x_kernel<<<3760, 256, 0, stream>>>(x, xbf);
    wtrans_kernel<<<2048, 256, 0, stream>>>(cw, wt);
    hist_kernel<<<1875, 256, 0, stream>>>(edst, counts);
    scan1_kernel<<<NB_SCAN, 256, 0, stream>>>(counts, locexcl, bsum);
    scan2_kernel<<<1, 128, 0, stream>>>(bsum, bpre);
    scan3_kernel<<<NB_SCAN, 256, 0, stream>>>(locexcl, bpre, offsets, cursor);
    gemm_kernel<<<dim3(235, 16), 256, 0, stream>>>(xbf, wt, al, ar, feat, projl, projr);
    logits_scatter_kernel<<<1875, 256, 0, stream>>>(esrc, edst, etyp, projl, projr,
                                                    cursor, srcoff, exw);
    aggregate_kernel<<<7500, 256, 0, stream>>>(offsets, srcoff, exw, feat, bias, out);
}

// Round 6
// 258.671 us; speedup vs baseline: 1.6538x; 1.0468x over previous
//
#include <hip/hip_runtime.h>

// Problem constants
#define N_NODES 30000
#define NPAD    30080            // 235 * 128
#define N_EDGES 480000
#define N_RELS  8
#define NB_SCAN 118              // ceil(30000/256)

typedef short bf16x8 __attribute__((ext_vector_type(8)));
typedef float f32x4  __attribute__((ext_vector_type(4)));

__device__ __forceinline__ unsigned short f2bf(float f) {
    unsigned u = __float_as_uint(f);
    u += 0x7fffu + ((u >> 16) & 1u);     // round-to-nearest-even
    return (unsigned short)(u >> 16);
}
__device__ __forceinline__ float bf2f(unsigned short h) {
    return __uint_as_float(((unsigned)h) << 16);
}

__device__ __forceinline__ void load_lds16(const void* g, void* l) {
    __builtin_amdgcn_global_load_lds(
        (const __attribute__((address_space(1))) unsigned int*)g,
        (__attribute__((address_space(3))) unsigned int*)l,
        16, 0, 0);
}

// ---------------------------------------------------------------------------
// K1: cast inputs fp32 -> bf16, pad rows [30000,30080) with zeros
// ---------------------------------------------------------------------------
__global__ void cast_x_kernel(const float* __restrict__ x, unsigned short* __restrict__ xbf) {
    int t = blockIdx.x * 256 + threadIdx.x;          // 962560 threads, 8 elems each
    int base = t * 8;
    int n = base >> 8;
    unsigned short h[8];
    if (n < N_NODES) {
        float4 a = *(const float4*)(x + base);
        float4 b = *(const float4*)(x + base + 4);
        h[0]=f2bf(a.x); h[1]=f2bf(a.y); h[2]=f2bf(a.z); h[3]=f2bf(a.w);
        h[4]=f2bf(b.x); h[5]=f2bf(b.y); h[6]=f2bf(b.z); h[7]=f2bf(b.w);
    } else {
        #pragma unroll
        for (int i = 0; i < 8; ++i) h[i] = 0;
    }
    uint4 o;
    o.x = (unsigned)h[0] | ((unsigned)h[1] << 16);
    o.y = (unsigned)h[2] | ((unsigned)h[3] << 16);
    o.z = (unsigned)h[4] | ((unsigned)h[5] << 16);
    o.w = (unsigned)h[6] | ((unsigned)h[7] << 16);
    *(uint4*)(xbf + base) = o;
}

// ---------------------------------------------------------------------------
// K2: transpose conv_weights [R,H,IN,D] fp32 -> wt[r][c][i] bf16, c = h*64+d
// ---------------------------------------------------------------------------
__global__ void wtrans_kernel(const float* __restrict__ cw, unsigned short* __restrict__ wt) {
    int o = blockIdx.x * 256 + threadIdx.x;          // 524288 threads
    if (o >= N_RELS * 256 * 256) return;
    int i = o & 255;
    int c = (o >> 8) & 255;
    int r = o >> 16;
    float v = cw[(((size_t)r * 4 + (c >> 6)) * 256 + i) * 64 + (c & 63)];
    wt[o] = f2bf(v);
}

// ---------------------------------------------------------------------------
// K2b: histogram of destination nodes
// ---------------------------------------------------------------------------
__global__ void hist_kernel(const int* __restrict__ edst, int* __restrict__ counts) {
    int e = blockIdx.x * 256 + threadIdx.x;
    if (e < N_EDGES) atomicAdd(&counts[edst[e]], 1);
}

// ---------------------------------------------------------------------------
// K2c/d/e: three-phase exclusive scan of counts -> offsets (+cursor copy)
// ---------------------------------------------------------------------------
__global__ void scan1_kernel(const int* __restrict__ counts, int* __restrict__ locexcl,
                             int* __restrict__ bsum) {
    __shared__ int sm[256];
    int tid = threadIdx.x;
    int idx = blockIdx.x * 256 + tid;
    int v = (idx < N_NODES) ? counts[idx] : 0;
    sm[tid] = v;
    __syncthreads();
    for (int o = 1; o < 256; o <<= 1) {
        int t = (tid >= o) ? sm[tid - o] : 0;
        __syncthreads();
        sm[tid] += t;
        __syncthreads();
    }
    int incl = sm[tid];
    if (idx < N_NODES) locexcl[idx] = incl - v;
    if (tid == 255) bsum[blockIdx.x] = incl;
}

__global__ void scan2_kernel(const int* __restrict__ bsum, int* __restrict__ bpre) {
    __shared__ int sm[128];
    int tid = threadIdx.x;
    int v = (tid < NB_SCAN) ? bsum[tid] : 0;
    sm[tid] = v;
    __syncthreads();
    for (int o = 1; o < 128; o <<= 1) {
        int t = (tid >= o) ? sm[tid - o] : 0;
        __syncthreads();
        sm[tid] += t;
        __syncthreads();
    }
    if (tid < NB_SCAN) bpre[tid] = sm[tid] - v;
}

__global__ void scan3_kernel(const int* __restrict__ locexcl, const int* __restrict__ bpre,
                             int* __restrict__ offsets, int* __restrict__ cursor) {
    int idx = blockIdx.x * 256 + threadIdx.x;
    if (idx < N_NODES) {
        int o = bpre[blockIdx.x] + locexcl[idx];
        offsets[idx] = o;
        cursor[idx]  = o;
    }
    if (idx == 0) offsets[N_NODES] = N_EDGES;
}

// ---------------------------------------------------------------------------
// K3: bf16 MFMA GEMM  feat[r][n][c] = sum_k xbf[n][k] * wt[r][c][k]
//     128x128 tile, BK=32, global_load_lds(16B).
//     XOR chunk swizzle on LDS staging kills the 8-way ds_read_b128 bank
//     conflicts of the plain layout (bank = 16*(row%2)+4*cc+d -> max 2-way).
//     Block-id remap: 16 consecutive blocks share one A-tile (L2-hot).
//     Fused epilogue 2: proj via per-wave LDS reduction (NOT lane shuffles —
//     shuffle-butterfly over MFMA accumulators failed on HW, rounds 1 & 4).
// ---------------------------------------------------------------------------
__global__ __launch_bounds__(256) void gemm_kernel(
    const unsigned short* __restrict__ xbf,   // [NPAD][256]
    const unsigned short* __restrict__ wt,    // [R][256][256]
    const float* __restrict__ attn_l,         // [R][4][64]
    const float* __restrict__ attn_r,
    unsigned short* __restrict__ feat,        // [R][NPAD][256]
    float* __restrict__ projl,                // [R][NPAD][4]
    float* __restrict__ projr)
{
    // first 16 KB: A|B staging during K-loop, then proj-L reduction buffer;
    // upper 16 KB: proj-R reduction buffer.
    __shared__ __align__(16) unsigned char smem[32768];

    const int tid  = threadIdx.x;
    const int lane = tid & 63;
    const int w    = tid >> 6;        // wave 0..3
    const int wm   = w >> 1;          // wave row (0/1)
    const int wn   = w & 1;           // wave col (0/1)
    const int quad = lane >> 4;
    const int l15  = lane & 15;

    const int bid = blockIdx.x;                // 0..3759
    const int mt  = bid >> 4;                  // 0..234  (16 consecutive blocks share A-tile)
    const int r   = (bid >> 1) & 7;            // relation
    const int nt  = bid & 1;                   // col tile (0/1)
    const int mbase = mt * 128;
    const int nbase = nt * 128;

    const unsigned short* Asrc = xbf + (size_t)mbase * 256;
    const unsigned short* Bsrc = wt + ((size_t)r * 256 + nbase) * 256;

    f32x4 acc[4][4] = {};

    // staging: lane's LDS slot is linear L = w*64+lane -> (row srow, chunk c0);
    // it must hold GLOBAL chunk c0 ^ ((row>>1)&3)  (XOR swizzle)
    const int srow = w * 16 + (lane >> 2);
    const int c0   = lane & 3;

    for (int k0 = 0; k0 < 256; k0 += 32) {
        #pragma unroll
        for (int n = 0; n < 2; ++n) {
            int row = n * 64 + srow;
            int c   = c0 ^ ((row >> 1) & 3);
            load_lds16(Asrc + (size_t)row * 256 + k0 + c * 8, smem + (n * 256 + w * 64) * 16);
        }
        #pragma unroll
        for (int n = 0; n < 2; ++n) {
            int row = n * 64 + srow;
            int c   = c0 ^ ((row >> 1) & 3);
            load_lds16(Bsrc + (size_t)row * 256 + k0 + c * 8, smem + 8192 + (n * 256 + w * 64) * 16);
        }
        __syncthreads();

        bf16x8 af[4], bfr[4];
        #pragma unroll
        for (int i = 0; i < 4; ++i) {
            int row = wm * 64 + i * 16 + l15;
            int cc  = quad ^ ((row >> 1) & 3);
            af[i] = *(const bf16x8*)(smem + row * 64 + cc * 16);
        }
        #pragma unroll
        for (int j = 0; j < 4; ++j) {
            int row = wn * 64 + j * 16 + l15;
            int cc  = quad ^ ((row >> 1) & 3);
            bfr[j] = *(const bf16x8*)(smem + 8192 + row * 64 + cc * 16);
        }

        #pragma unroll
        for (int i = 0; i < 4; ++i)
            #pragma unroll
            for (int j = 0; j < 4; ++j)
                acc[i][j] = __builtin_amdgcn_mfma_f32_16x16x32_bf16(af[i], bfr[j], acc[i][j], 0, 0, 0);
        __syncthreads();
    }

    // ---- epilogue 1: feat bf16, direct stores in C-layout (row=quad*4+e, col=l15)
    size_t obase = ((size_t)r * NPAD + mbase + wm * 64) * 256 + nbase + wn * 64;
    #pragma unroll
    for (int i = 0; i < 4; ++i)
        #pragma unroll
        for (int j = 0; j < 4; ++j)
            #pragma unroll
            for (int e = 0; e < 4; ++e)
                feat[obase + (size_t)(i * 16 + quad * 4 + e) * 256 + j * 16 + l15] = f2bf(acc[i][j][e]);

    // ---- epilogue 2: fused attention projections via per-wave LDS reduction.
    // Each wave touches only its own disjoint 4KB region -> no __syncthreads.
    const int head = nt * 2 + wn;
    float al[4], ar[4];
    #pragma unroll
    for (int j = 0; j < 4; ++j) {
        al[j] = attn_l[((size_t)r * 4 + head) * 64 + j * 16 + l15];
        ar[j] = attn_r[((size_t)r * 4 + head) * 64 + j * 16 + l15];
    }
    float* bufL = (float*)smem + w * 1024;            // 64 rows x 16 partials
    float* bufR = (float*)(smem + 16384) + w * 1024;
    #pragma unroll
    for (int i = 0; i < 4; ++i)
        #pragma unroll
        for (int e = 0; e < 4; ++e) {
            float s1 = 0.f, s2 = 0.f;
            #pragma unroll
            for (int j = 0; j < 4; ++j) {
                s1 += acc[i][j][e] * al[j];
                s2 += acc[i][j][e] * ar[j];
            }
            int row = i * 16 + quad * 4 + e;          // local row, 0..63
            bufL[row * 16 + l15] = s1;
            bufR[row * 16 + l15] = s2;
        }
    float sL = 0.f, sR = 0.f;
    #pragma unroll
    for (int c = 0; c < 4; ++c) {
        float4 vl = *(const float4*)(bufL + lane * 16 + c * 4);
        float4 vr = *(const float4*)(bufR + lane * 16 + c * 4);
        sL += (vl.x + vl.y) + (vl.z + vl.w);
        sR += (vr.x + vr.y) + (vr.z + vr.w);
    }
    int g = mbase + wm * 64 + lane;
    projl[((size_t)r * NPAD + g) * 4 + head] = sL;
    projr[((size_t)r * NPAD + g) * 4 + head] = sR;
}

// ---------------------------------------------------------------------------
// K4: fused per-edge logits + CSR scatter with payload:
//     srcoff[p] = t*NPAD+s  and  exw[p] = float4 of exp(leaky_relu(el+er))
// ---------------------------------------------------------------------------
__global__ void logits_scatter_kernel(
    const int* __restrict__ esrc, const int* __restrict__ edst, const int* __restrict__ etyp,
    const float* __restrict__ projl, const float* __restrict__ projr,
    int* __restrict__ cursor, int* __restrict__ srcoff, float* __restrict__ exw)
{
    int e = blockIdx.x * 256 + threadIdx.x;
    if (e >= N_EDGES) return;
    int s = esrc[e], d = edst[e], t = etyp[e];
    float4 pl = ((const float4*)projl)[(size_t)t * NPAD + s];
    float4 pr = ((const float4*)projr)[(size_t)t * NPAD + d];
    float4 o;
    float v;
    v = pl.x + pr.x; v = v > 0.f ? v : 0.2f * v; o.x = __expf(v);
    v = pl.y + pr.y; v = v > 0.f ? v : 0.2f * v; o.y = __expf(v);
    v = pl.z + pr.z; v = v > 0.f ? v : 0.2f * v; o.z = __expf(v);
    v = pl.w + pr.w; v = v > 0.f ? v : 0.2f * v; o.w = __expf(v);
    int p = atomicAdd(&cursor[d], 1);
    srcoff[p] = t * NPAD + s;
    ((float4*)exw)[p] = o;
}

// ---------------------------------------------------------------------------
// K7: per-node aggregation: one wave per dst node (4 nodes / block).
//     Streams srcoff/exw sequentially; 4 independent feat gathers in flight.
// ---------------------------------------------------------------------------
__global__ __launch_bounds__(256) void aggregate_kernel(
    const int* __restrict__ offsets, const int* __restrict__ srcoff,
    const float* __restrict__ exw, const unsigned short* __restrict__ feat,
    const float* __restrict__ bias, float* __restrict__ out)
{
    int v = blockIdx.x * 4 + (threadIdx.x >> 6);   // grid 7500 -> v < 30000
    int lane = threadIdx.x & 63;
    int head = lane >> 4;
    int s0 = offsets[v], s1 = offsets[v + 1];
    float a0 = 0.f, a1 = 0.f, a2 = 0.f, a3 = 0.f, den = 0.f;
    int i = s0;
    for (; i + 4 <= s1; i += 4) {
        int o0 = srcoff[i], o1 = srcoff[i + 1], o2 = srcoff[i + 2], o3 = srcoff[i + 3];
        float e0 = exw[(size_t)i * 4 + head];
        float e1 = exw[(size_t)(i + 1) * 4 + head];
        float e2 = exw[(size_t)(i + 2) * 4 + head];
        float e3 = exw[(size_t)(i + 3) * 4 + head];
        ushort4 f0 = *(const ushort4*)(feat + (size_t)o0 * 256 + lane * 4);
        ushort4 f1 = *(const ushort4*)(feat + (size_t)o1 * 256 + lane * 4);
        ushort4 f2 = *(const ushort4*)(feat + (size_t)o2 * 256 + lane * 4);
        ushort4 f3 = *(const ushort4*)(feat + (size_t)o3 * 256 + lane * 4);
        den += (e0 + e1) + (e2 + e3);
        a0 += e0 * bf2f(f0.x) + e1 * bf2f(f1.x) + e2 * bf2f(f2.x) + e3 * bf2f(f3.x);
        a1 += e0 * bf2f(f0.y) + e1 * bf2f(f1.y) + e2 * bf2f(f2.y) + e3 * bf2f(f3.y);
        a2 += e0 * bf2f(f0.z) + e1 * bf2f(f1.z) + e2 * bf2f(f2.z) + e3 * bf2f(f3.z);
        a3 += e0 * bf2f(f0.w) + e1 * bf2f(f1.w) + e2 * bf2f(f2.w) + e3 * bf2f(f3.w);
    }
    for (; i < s1; ++i) {
        int o0 = srcoff[i];
        float e0 = exw[(size_t)i * 4 + head];
        ushort4 f0 = *(const ushort4*)(feat + (size_t)o0 * 256 + lane * 4);
        den += e0;
        a0 += e0 * bf2f(f0.x);
        a1 += e0 * bf2f(f0.y);
        a2 += e0 * bf2f(f0.z);
        a3 += e0 * bf2f(f0.w);
    }
    float inv = den > 0.f ? 1.f / den : 0.f;
    float4 o;
    o.x = a0 * inv + bias[lane * 4 + 0];
    o.y = a1 * inv + bias[lane * 4 + 1];
    o.z = a2 * inv + bias[lane * 4 + 2];
    o.w = a3 * inv + bias[lane * 4 + 3];
    ((float4*)out)[(size_t)v * 64 + lane] = o;
}

// ---------------------------------------------------------------------------
extern "C" void kernel_launch(void* const* d_in, const int* in_sizes, int n_in,
                              void* d_out, int out_size, void* d_ws, size_t ws_size,
                              hipStream_t stream) {
    const float* x    = (const float*)d_in[0];
    const float* cw   = (const float*)d_in[1];
    const float* al   = (const float*)d_in[2];
    const float* ar   = (const float*)d_in[3];
    const float* bias = (const float*)d_in[4];
    const int* esrc   = (const int*)d_in[5];
    const int* edst   = (const int*)d_in[6];
    const int* etyp   = (const int*)d_in[7];
    float* out        = (float*)d_out;

    char* ws = (char*)d_ws;
    size_t off = 0;
    auto alloc = [&](size_t bytes) { size_t o = off; off += (bytes + 255) & ~(size_t)255; return o; };

    unsigned short* xbf  = (unsigned short*)(ws + alloc((size_t)NPAD * 256 * 2));          // 15.4 MB
    unsigned short* wt   = (unsigned short*)(ws + alloc((size_t)N_RELS * 256 * 256 * 2));  // 1 MB
    unsigned short* feat = (unsigned short*)(ws + alloc((size_t)N_RELS * NPAD * 256 * 2)); // 123.2 MB
    float* projl = (float*)(ws + alloc((size_t)N_RELS * NPAD * 4 * 4));                    // 3.85 MB
    float* projr = (float*)(ws + alloc((size_t)N_RELS * NPAD * 4 * 4));                    // 3.85 MB
    float* exw   = (float*)(ws + alloc((size_t)N_EDGES * 4 * 4));                          // 7.68 MB
    int* srcoff  = (int*)(ws + alloc((size_t)N_EDGES * 4));                                // 1.92 MB
    int* counts  = (int*)(ws + alloc((size_t)N_NODES * 4));
    int* offsets = (int*)(ws + alloc((size_t)(N_NODES + 1) * 4));
    int* cursor  = (int*)(ws + alloc((size_t)N_NODES * 4));
    int* locexcl = (int*)(ws + alloc((size_t)N_NODES * 4));
    int* bsum    = (int*)(ws + alloc((size_t)NB_SCAN * 4));
    int* bpre    = (int*)(ws + alloc((size_t)NB_SCAN * 4));

    hipMemsetAsync(counts, 0, (size_t)N_NODES * 4, stream);

    cast_x_kernel<<<3760, 256, 0, stream>>>(x, xbf);
    wtrans_kernel<<<2048, 256, 0, stream>>>(cw, wt);
    hist_kernel<<<1875, 256, 0, stream>>>(edst, counts);
    scan1_kernel<<<NB_SCAN, 256, 0, stream>>>(counts, locexcl, bsum);
    scan2_kernel<<<1, 128, 0, stream>>>(bsum, bpre);
    scan3_kernel<<<NB_SCAN, 256, 0, stream>>>(locexcl, bpre, offsets, cursor);
    gemm_kernel<<<3760, 256, 0, stream>>>(xbf, wt, al, ar, feat, projl, projr);
    logits_scatter_kernel<<<1875, 256, 0, stream>>>(esrc, edst, etyp, projl, projr,
                                                    cursor, srcoff, exw);
    aggregate_kernel<<<7500, 256, 0, stream>>>(offsets, srcoff, exw, feat, bias, out);
}